// Round 4
// baseline (2963.563 us; speedup 1.0000x reference)
//
#include <hip/hip_runtime.h>
#include <hip/hip_fp16.h>
#include <math.h>

#define HDIM 2048
#define ANUM 16
#define GRID 512          // 2 blocks/CU × 256 CUs — co-residency guaranteed (see launch_bounds)
#define ROWS 4            // rows per block per phase: b + i*GRID
#define SUBC 16
#define PERSUB (GRID / SUBC)
#define BARSTRIDE (18 * 32)   // ints per barrier record: 16 subs + super + flag, 128B-padded
#define NBAR 48
#define SCOPE_AGENT __HIP_MEMORY_SCOPE_AGENT

typedef float f32x4 __attribute__((ext_vector_type(4)));

struct Shared {
    float red[4][4][ROWS];
    float smr[4];
};

__device__ __forceinline__ float wave_sum(float v) {
#pragma unroll
    for (int off = 32; off > 0; off >>= 1) v += __shfl_down(v, off, 64);
    return v;
}
__device__ __forceinline__ float wave_max(float v) {
#pragma unroll
    for (int off = 32; off > 0; off >>= 1) v = fmaxf(v, __shfl_down(v, off, 64));
    return v;
}
__device__ __forceinline__ float dotv(f32x4 a, f32x4 b) {
    return a.x * b.x + a.y * b.y + a.z * b.z + a.w * b.w;
}
__device__ __forceinline__ float dot_u4(uint4 a, f32x4 v0, f32x4 v1) {
    float2 f; float s = 0.f;
    f = __half22float2(*(__half2*)&a.x); s += f.x * v0.x + f.y * v0.y;
    f = __half22float2(*(__half2*)&a.y); s += f.x * v0.z + f.y * v0.w;
    f = __half22float2(*(__half2*)&a.z); s += f.x * v1.x + f.y * v1.y;
    f = __half22float2(*(__half2*)&a.w); s += f.x * v1.z + f.y * v1.w;
    return s;
}
__device__ __forceinline__ uint4 pack8(f32x4 a, f32x4 b) {
    __half2 p0 = __floats2half2_rn(a.x, a.y);
    __half2 p1 = __floats2half2_rn(a.z, a.w);
    __half2 p2 = __floats2half2_rn(b.x, b.y);
    __half2 p3 = __floats2half2_rn(b.z, b.w);
    uint4 o;
    o.x = *(unsigned int*)&p0; o.y = *(unsigned int*)&p1;
    o.z = *(unsigned int*)&p2; o.w = *(unsigned int*)&p3;
    return o;
}

// Zero all barrier records. Runs every launch (replays must start clean).
__global__ __launch_bounds__(256) void init_bar_kernel(int* __restrict__ bar) {
    int i = blockIdx.x * 256 + threadIdx.x;
    if (i < NBAR * BARSTRIDE) bar[i] = 0;
}

// Grid barrier #k. Caller must: (1) execute a release fence on ALL threads,
// (2) optionally issue prefetch loads, (3) asm compiler-barrier, then call this.
// t0 arrives on a sub-counter; last sub-arrival bumps super; last super sets flag.
__device__ __forceinline__ void gbar_wait(int k, int* bar) {
    __syncthreads();
    if (threadIdx.x == 0) {
        int* rec = bar + k * BARSTRIDE;
        const int sub = (int)(blockIdx.x & (SUBC - 1));
        int old = __hip_atomic_fetch_add(rec + sub * 32, 1, __ATOMIC_RELAXED, SCOPE_AGENT);
        if (old == PERSUB - 1) {
            int o2 = __hip_atomic_fetch_add(rec + SUBC * 32, 1, __ATOMIC_RELAXED, SCOPE_AGENT);
            if (o2 == SUBC - 1)
                __hip_atomic_store(rec + 17 * 32, 1, __ATOMIC_RELAXED, SCOPE_AGENT);
        }
        while (__hip_atomic_load(rec + 17 * 32, __ATOMIC_RELAXED, SCOPE_AGENT) == 0)
            __builtin_amdgcn_s_sleep(8);
    }
    __syncthreads();
    __builtin_amdgcn_fence(__ATOMIC_ACQUIRE, "agent");  // drains vmcnt (prefetch ~done) + inv L2
}

__device__ __forceinline__ void block_softmax(const float* logits, int t,
                                              f32x4& x0, f32x4& x1, Shared* sh) {
    const f32x4* l4 = (const f32x4*)logits;
    f32x4 v0 = l4[2 * t], v1 = l4[2 * t + 1];
    float m = fmaxf(fmaxf(fmaxf(v0.x, v0.y), fmaxf(v0.z, v0.w)),
                    fmaxf(fmaxf(v1.x, v1.y), fmaxf(v1.z, v1.w)));
    m = wave_max(m);
    if ((t & 63) == 0) sh->smr[t >> 6] = m;
    __syncthreads();
    m = fmaxf(fmaxf(sh->smr[0], sh->smr[1]), fmaxf(sh->smr[2], sh->smr[3]));
    f32x4 e0, e1;
    e0.x = expf(v0.x - m); e0.y = expf(v0.y - m); e0.z = expf(v0.z - m); e0.w = expf(v0.w - m);
    e1.x = expf(v1.x - m); e1.y = expf(v1.y - m); e1.z = expf(v1.z - m); e1.w = expf(v1.w - m);
    float s = e0.x + e0.y + e0.z + e0.w + e1.x + e1.y + e1.z + e1.w;
    s = wave_sum(s);
    __syncthreads();                       // smr reuse safety
    if ((t & 63) == 0) sh->smr[t >> 6] = s;
    __syncthreads();
    const float inv = 1.f / (sh->smr[0] + sh->smr[1] + sh->smr[2] + sh->smr[3]);
    x0 = e0 * inv; x1 = e1 * inv;
}

__device__ __forceinline__ void cell4(int t, int b, float (*acc)[4],
                                      const float (*bs)[4], float* c,
                                      float* hdst_base, Shared* sh) {
    const int wave = t >> 6, lane = t & 63;
#pragma unroll
    for (int i = 0; i < ROWS; ++i)
#pragma unroll
        for (int g = 0; g < 4; ++g) {
            float v = wave_sum(acc[i][g]);
            if (lane == 0) sh->red[wave][g][i] = v;
        }
    __syncthreads();
    if (t == 0) {
#pragma unroll
        for (int i = 0; i < ROWS; ++i) {
            float gi = sh->red[0][0][i] + sh->red[1][0][i] + sh->red[2][0][i] + sh->red[3][0][i] + bs[i][0];
            float gf = sh->red[0][1][i] + sh->red[1][1][i] + sh->red[2][1][i] + sh->red[3][1][i] + bs[i][1];
            float gg = sh->red[0][2][i] + sh->red[1][2][i] + sh->red[2][2][i] + sh->red[3][2][i] + bs[i][2];
            float go = sh->red[0][3][i] + sh->red[1][3][i] + sh->red[2][3][i] + sh->red[3][3][i] + bs[i][3];
            float si = 1.f / (1.f + expf(-gi));
            float sf = 1.f / (1.f + expf(-gf));
            float so = 1.f / (1.f + expf(-go));
            float tg = tanhf(gg);
            float cn = sf * c[i] + si * tg;
            c[i] = cn;
            hdst_base[b + i * GRID] = so * tanhf(cn);
        }
    }
}

// fp16 LSTM layer phase, 4 rows/block, software-pipelined (pf holds row0, preloaded).
__device__ __forceinline__ void phase_f16_4(int t, int b, f32x4 x0, f32x4 x1,
                                            f32x4 h0, f32x4 h1, uint4* pf,
                                            const uint4* Wih, const uint4* Whh,
                                            const float (*bs)[4], float* c,
                                            float* hdst_base, Shared* sh) {
    float acc[ROWS][4];
    uint4 wn[8];
#pragma unroll
    for (int g = 0; g < 4; ++g) {           // issue row1
        const size_t rv = (size_t)(g * HDIM + b + GRID);
        wn[g]     = Wih[rv * 256 + t];
        wn[4 + g] = Whh[rv * 256 + t];
    }
#pragma unroll
    for (int g = 0; g < 4; ++g)              // row0 from prefetch
        acc[0][g] = dot_u4(pf[g], x0, x1) + dot_u4(pf[4 + g], h0, h1);
#pragma unroll
    for (int g = 0; g < 4; ++g) {            // issue row2 (reuse pf regs)
        const size_t rv = (size_t)(g * HDIM + b + 2 * GRID);
        pf[g]     = Wih[rv * 256 + t];
        pf[4 + g] = Whh[rv * 256 + t];
    }
#pragma unroll
    for (int g = 0; g < 4; ++g)
        acc[1][g] = dot_u4(wn[g], x0, x1) + dot_u4(wn[4 + g], h0, h1);
#pragma unroll
    for (int g = 0; g < 4; ++g) {            // issue row3
        const size_t rv = (size_t)(g * HDIM + b + 3 * GRID);
        wn[g]     = Wih[rv * 256 + t];
        wn[4 + g] = Whh[rv * 256 + t];
    }
#pragma unroll
    for (int g = 0; g < 4; ++g)
        acc[2][g] = dot_u4(pf[g], x0, x1) + dot_u4(pf[4 + g], h0, h1);
#pragma unroll
    for (int g = 0; g < 4; ++g)
        acc[3][g] = dot_u4(wn[g], x0, x1) + dot_u4(wn[4 + g], h0, h1);
    cell4(t, b, acc, bs, c, hdst_base, sh);
}

__device__ __forceinline__ void gemv_reduce(int t, int b, const float* v,
                                            const float* bo, float* logits, Shared* sh) {
    const int wave = t >> 6, lane = t & 63;
#pragma unroll
    for (int i = 0; i < ROWS; ++i) {
        float s = wave_sum(v[i]);
        if (lane == 0) sh->red[wave][0][i] = s;
    }
    __syncthreads();
    if (t == 0) {
#pragma unroll
        for (int i = 0; i < ROWS; ++i)
            logits[b + i * GRID] = sh->red[0][0][i] + sh->red[1][0][i]
                                 + sh->red[2][0][i] + sh->red[3][0][i] + bo[i];
    }
}

__global__ __launch_bounds__(256, 2) void policy_persistent_kernel(
    const float* __restrict__ x,
    const float* __restrict__ Wih32, const float* __restrict__ Whh32,
    const float* __restrict__ bih, const float* __restrict__ bhh,
    const float* __restrict__ Wout32, const float* __restrict__ bout,
    float* __restrict__ out,
    float* hbuf, float* logits,
    uint4* Wih16, uint4* Whh16, uint4* Wout16,
    int* bar)
{
    const int b = (int)blockIdx.x, t = (int)threadIdx.x;
    __shared__ Shared sh;

    const uint4* WihL0 = Wih16;
    const uint4* WhhL0 = Whh16;
    const uint4* WihL1 = Wih16 + (size_t)4 * HDIM * HDIM / 8;
    const uint4* WhhL1 = Whh16 + (size_t)4 * HDIM * HDIM / 8;
    const float* Wih32L1 = Wih32 + (size_t)4 * HDIM * HDIM;
    const float* Whh32L1 = Whh32 + (size_t)4 * HDIM * HDIM;

    // Per-block persistent state: biases (uniform per block) + cell state in regs.
    float bsA[ROWS][4], bsB[ROWS][4], bo[ROWS];
#pragma unroll
    for (int i = 0; i < ROWS; ++i) {
        const int r = b + i * GRID;
#pragma unroll
        for (int g = 0; g < 4; ++g) {
            bsA[i][g] = bih[g * HDIM + r] + bhh[g * HDIM + r];
            bsB[i][g] = bih[4 * HDIM + g * HDIM + r] + bhh[4 * HDIM + g * HDIM + r];
        }
        bo[i] = bout[r];
    }
    float cA[ROWS] = {0.f, 0.f, 0.f, 0.f}, cB[ROWS] = {0.f, 0.f, 0.f, 0.f};

    uint4 pf[8];
    uint4 pc[ROWS];

    // ===== step 0: fp32 weights (nt loads), h=0 (skip W_hh dot), write fp16 copies =====
    {
        const f32x4* xp = (const f32x4*)x;
        const f32x4 x0 = xp[2 * t], x1 = xp[2 * t + 1];
        {   // A0
            float acc[ROWS][4];
#pragma unroll
            for (int i = 0; i < ROWS; ++i) {
                const int r = b + i * GRID;
#pragma unroll
                for (int g = 0; g < 4; ++g) {
                    const size_t rv = (size_t)(g * HDIM + r);
                    const f32x4* wi = (const f32x4*)(Wih32 + rv * HDIM);
                    f32x4 wa = __builtin_nontemporal_load(wi + 2 * t);
                    f32x4 wb = __builtin_nontemporal_load(wi + 2 * t + 1);
                    acc[i][g] = dotv(wa, x0) + dotv(wb, x1);
                    Wih16[rv * 256 + t] = pack8(wa, wb);
                    const f32x4* wh = (const f32x4*)(Whh32 + rv * HDIM);
                    f32x4 wc = __builtin_nontemporal_load(wh + 2 * t);
                    f32x4 wd = __builtin_nontemporal_load(wh + 2 * t + 1);
                    Whh16[rv * 256 + t] = pack8(wc, wd);
                }
            }
            cell4(t, b, acc, bsA, cA, hbuf + 2 * HDIM, &sh);      // write par1,L0
            __builtin_amdgcn_fence(__ATOMIC_RELEASE, "agent");
            gbar_wait(0, bar);
        }
        {   // B0
            const f32x4* xp2 = (const f32x4*)(hbuf + 2 * HDIM);
            const f32x4 y0 = xp2[2 * t], y1 = xp2[2 * t + 1];
            float acc[ROWS][4];
#pragma unroll
            for (int i = 0; i < ROWS; ++i) {
                const int r = b + i * GRID;
#pragma unroll
                for (int g = 0; g < 4; ++g) {
                    const size_t rv = (size_t)(g * HDIM + r);
                    const f32x4* wi = (const f32x4*)(Wih32L1 + rv * HDIM);
                    f32x4 wa = __builtin_nontemporal_load(wi + 2 * t);
                    f32x4 wb = __builtin_nontemporal_load(wi + 2 * t + 1);
                    acc[i][g] = dotv(wa, y0) + dotv(wb, y1);
                    const_cast<uint4*>(WihL1)[rv * 256 + t] = pack8(wa, wb);
                    const f32x4* wh = (const f32x4*)(Whh32L1 + rv * HDIM);
                    f32x4 wc = __builtin_nontemporal_load(wh + 2 * t);
                    f32x4 wd = __builtin_nontemporal_load(wh + 2 * t + 1);
                    const_cast<uint4*>(WhhL1)[rv * 256 + t] = pack8(wc, wd);
                }
            }
            cell4(t, b, acc, bsB, cB, hbuf + 2 * HDIM + HDIM, &sh);  // par1,L1
            __builtin_amdgcn_fence(__ATOMIC_RELEASE, "agent");
            gbar_wait(1, bar);
        }
        {   // C0 (out gemv, fp32 + convert)
            const f32x4* hp = (const f32x4*)(hbuf + 2 * HDIM + HDIM);
            f32x4 h0 = hp[2 * t], h1 = hp[2 * t + 1];
            float v[ROWS];
#pragma unroll
            for (int i = 0; i < ROWS; ++i) {
                const int r = b + i * GRID;
                const f32x4* w = (const f32x4*)(Wout32 + (size_t)r * HDIM);
                f32x4 wa = __builtin_nontemporal_load(w + 2 * t);
                f32x4 wb = __builtin_nontemporal_load(w + 2 * t + 1);
                v[i] = dotv(wa, h0) + dotv(wb, h1);
                Wout16[(size_t)r * 256 + t] = pack8(wa, wb);
            }
            gemv_reduce(t, b, v, bo, logits, &sh);
            __builtin_amdgcn_fence(__ATOMIC_RELEASE, "agent");
#pragma unroll
            for (int g = 0; g < 4; ++g) {   // prefetch A1 row b (own rows, written in A0)
                const size_t rv = (size_t)(g * HDIM + b);
                pf[g]     = WihL0[rv * 256 + t];
                pf[4 + g] = WhhL0[rv * 256 + t];
            }
            asm volatile("" ::: "memory");
            gbar_wait(2, bar);
        }
    }

    // ===== steps 1..15: fp16 =====
    for (int s = 1; s < ANUM; ++s) {
        const int rp = s & 1, wp = rp ^ 1;
        {   // A: softmax(logits) -> x; LSTM layer 0
            const f32x4* hp = (const f32x4*)(hbuf + rp * 2 * HDIM);
            f32x4 h0 = hp[2 * t], h1 = hp[2 * t + 1];   // issued before softmax VALU work
            f32x4 x0, x1;
            block_softmax(logits, t, x0, x1, &sh);
            if (b == 0) {
                f32x4* op = (f32x4*)(out + (size_t)(s - 1) * HDIM);
                op[2 * t] = x0; op[2 * t + 1] = x1;
            }
            phase_f16_4(t, b, x0, x1, h0, h1, pf, WihL0, WhhL0, bsA, cA,
                        hbuf + wp * 2 * HDIM, &sh);
            __builtin_amdgcn_fence(__ATOMIC_RELEASE, "agent");
#pragma unroll
            for (int g = 0; g < 4; ++g) {   // prefetch B row b (L1)
                const size_t rv = (size_t)(g * HDIM + b);
                pf[g]     = WihL1[rv * 256 + t];
                pf[4 + g] = WhhL1[rv * 256 + t];
            }
            asm volatile("" ::: "memory");
            gbar_wait(3 * s, bar);
        }
        {   // B: LSTM layer 1
            const f32x4* xp2 = (const f32x4*)(hbuf + wp * 2 * HDIM);
            f32x4 x0 = xp2[2 * t], x1 = xp2[2 * t + 1];
            const f32x4* hp = (const f32x4*)(hbuf + rp * 2 * HDIM + HDIM);
            f32x4 h0 = hp[2 * t], h1 = hp[2 * t + 1];
            phase_f16_4(t, b, x0, x1, h0, h1, pf, WihL1, WhhL1, bsB, cB,
                        hbuf + wp * 2 * HDIM + HDIM, &sh);
            __builtin_amdgcn_fence(__ATOMIC_RELEASE, "agent");
#pragma unroll
            for (int i = 0; i < ROWS; ++i)  // prefetch C rows
                pc[i] = Wout16[(size_t)(b + i * GRID) * 256 + t];
            asm volatile("" ::: "memory");
            gbar_wait(3 * s + 1, bar);
        }
        {   // C: out gemv
            const f32x4* hp = (const f32x4*)(hbuf + wp * 2 * HDIM + HDIM);
            f32x4 h0 = hp[2 * t], h1 = hp[2 * t + 1];
            float v[ROWS];
#pragma unroll
            for (int i = 0; i < ROWS; ++i) v[i] = dot_u4(pc[i], h0, h1);
            gemv_reduce(t, b, v, bo, logits, &sh);
            __builtin_amdgcn_fence(__ATOMIC_RELEASE, "agent");
#pragma unroll
            for (int g = 0; g < 4; ++g) {   // prefetch next A row b (L0); harmless at s==15
                const size_t rv = (size_t)(g * HDIM + b);
                pf[g]     = WihL0[rv * 256 + t];
                pf[4 + g] = WhhL0[rv * 256 + t];
            }
            asm volatile("" ::: "memory");
            gbar_wait(3 * s + 2, bar);
        }
    }

    // final softmax -> out[15]
    if (b == 0) {
        f32x4 x0, x1;
        block_softmax(logits, t, x0, x1, &sh);
        f32x4* op = (f32x4*)(out + (size_t)(ANUM - 1) * HDIM);
        op[2 * t] = x0; op[2 * t + 1] = x1;
    }
}

extern "C" void kernel_launch(void* const* d_in, const int* in_sizes, int n_in,
                              void* d_out, int out_size, void* d_ws, size_t ws_size,
                              hipStream_t stream) {
    const float* x    = (const float*)d_in[0];
    const float* Wih  = (const float*)d_in[1];   // [L, 4H, H] fp32
    const float* Whh  = (const float*)d_in[2];   // [L, 4H, H] fp32
    const float* bih  = (const float*)d_in[3];   // [L, 4H]
    const float* bhh  = (const float*)d_in[4];   // [L, 4H]
    const float* Wout = (const float*)d_in[5];   // [S, H] fp32
    const float* bout = (const float*)d_in[6];   // [S]
    float* out = (float*)d_out;                  // [A, S] fp32

    float* wsf    = (float*)d_ws;
    float* hbuf   = wsf;                         // [2 par][2 layers][2048] = 8192 f
    float* logits = wsf + 4 * HDIM;              // 2048 f
    int*   bar    = (int*)(wsf + 5 * HDIM);      // 48 * 576 ints = 110592 B

    uint4* Wih16  = (uint4*)((char*)d_ws + (1 << 18));        // 256 KiB offset
    uint4* Whh16  = Wih16 + (size_t)HDIM * HDIM;              // 4194304 uint4 = 64 MiB each
    uint4* Wout16 = Whh16 + (size_t)HDIM * HDIM;              // + 8 MiB
    // total ws: ~136.3 MiB

    init_bar_kernel<<<(NBAR * BARSTRIDE + 255) / 256, 256, 0, stream>>>(bar);
    policy_persistent_kernel<<<GRID, 256, 0, stream>>>(
        x, Wih, Whh, bih, bhh, Wout, bout, out,
        hbuf, logits, Wih16, Whh16, Wout16, bar);
}